// Round 1
// baseline (289.614 us; speedup 1.0000x reference)
//
#include <hip/hip_runtime.h>
#include <stdint.h>

#define Bq 8
#define Cc 128
#define Hh 192
#define Ww 192
#define CROPW 38
#define CROPOFF 77
#define NPTS 11552    // 8*38*38
#define NPAD 11648    // 91*128
#define NT 91

typedef short bf16x8 __attribute__((ext_vector_type(8)));
typedef float f32x4 __attribute__((ext_vector_type(4)));
typedef unsigned short ushort;

__device__ __forceinline__ ushort f2bf(float f) {
  uint32_t b = __float_as_uint(f);
  uint32_t r = b + 0x7fffu + ((b >> 16) & 1u);
  return (ushort)(r >> 16);
}

__device__ __forceinline__ void g2l16(const void* g, void* l) {
  __builtin_amdgcn_global_load_lds(
      (const __attribute__((address_space(1))) unsigned int*)g,
      (__attribute__((address_space(3))) unsigned int*)l, 16, 0, 0);
}

// ---------------- init: min_neg=+inf, pos=0, padding rows zeroed ----------------
__global__ void init_k(ushort* __restrict__ aB, ushort* __restrict__ pB,
                       float* __restrict__ d1, float* __restrict__ d2,
                       float* __restrict__ pos, unsigned* __restrict__ mn) {
  int i = blockIdx.x * 256 + threadIdx.x;
  if (i >= NPAD) return;
  mn[i] = 0x7f800000u;  // +inf
  pos[i] = 0.f;
  if (i >= NPTS) {
    d1[i] = 0.f;
    d2[i] = 1e30f;  // padded columns never win the min
    for (int c = 0; c < 128; ++c) { aB[(size_t)i*128 + c] = 0; pB[(size_t)i*128 + c] = 0; }
  }
}

// ---------------- sample + pack: bilinear gather of feat2, crop of feat1 --------
__global__ __launch_bounds__(128) void sample_k(
    const float* __restrict__ feat1, const float* __restrict__ feat2,
    const float* __restrict__ aflow,
    ushort* __restrict__ aB, ushort* __restrict__ pB,
    float* __restrict__ d1, float* __restrict__ d2) {
  int idx = blockIdx.x;                     // 0..NPTS-1, row order matches reference reshape
  int b = idx / (CROPW * CROPW);
  int rem = idx % (CROPW * CROPW);
  int r = rem / CROPW, cx = rem % CROPW;
  int y = CROPOFF + r, x = CROPOFF + cx;
  int c = threadIdx.x;                      // channel

  float ax = aflow[(((size_t)b*2 + 0)*Hh + y)*Ww + x];
  float ay = aflow[(((size_t)b*2 + 1)*Hh + y)*Ww + x];
  // replicate reference's normalize->denormalize round trip exactly
  float gxn = ax * (2.0f/(Ww-1)) - 1.0f;
  float gyn = ay * (2.0f/(Hh-1)) - 1.0f;
  float gx = (gxn + 1.0f) * 0.5f * (Ww-1);
  float gy = (gyn + 1.0f) * 0.5f * (Hh-1);
  float x0 = floorf(gx), y0 = floorf(gy);
  float wx1 = gx - x0, wx0 = 1.f - wx1;
  float wy1 = gy - y0, wy0 = 1.f - wy1;

  const float* f2b = feat2 + ((size_t)b*Cc + c) * Hh * Ww;
  auto samp = [&](float xf, float yf) -> float {
    bool valid = (xf >= 0.f) && (xf <= (float)(Ww-1)) && (yf >= 0.f) && (yf <= (float)(Hh-1));
    int xi = (int)fminf(fmaxf(xf, 0.f), (float)(Ww-1));
    int yi = (int)fminf(fmaxf(yf, 0.f), (float)(Hh-1));
    float v = f2b[yi*Ww + xi];
    return valid ? v : 0.f;
  };
  float v = wx0*wy0*samp(x0,     y0    ) + wx1*wy0*samp(x0+1.f, y0    )
          + wx0*wy1*samp(x0,     y0+1.f) + wx1*wy1*samp(x0+1.f, y0+1.f);
  float f1v = feat1[((((size_t)b*Cc + c)*Hh) + y)*Ww + x];

  aB[(size_t)idx*128 + c] = f2bf(f1v);
  pB[(size_t)idx*128 + c] = f2bf(v);

  float s1 = f1v*f1v, s2 = v*v;
  for (int off = 1; off < 64; off <<= 1) { s1 += __shfl_xor(s1, off); s2 += __shfl_xor(s2, off); }
  __shared__ float red[4];
  if ((threadIdx.x & 63) == 0) { red[(threadIdx.x>>6)*2] = s1; red[(threadIdx.x>>6)*2+1] = s2; }
  __syncthreads();
  if (threadIdx.x == 0) { d1[idx] = red[0] + red[2]; d2[idx] = red[1] + red[3]; }
}

// ---------------- fused GEMM + distance epilogue + row-min --------------------
__global__ __launch_bounds__(256) void gemm_k(
    const ushort* __restrict__ aB, const ushort* __restrict__ pB,
    const float* __restrict__ d1, const float* __restrict__ d2,
    float* __restrict__ pos, unsigned* __restrict__ mn) {
  __shared__ __align__(16) ushort lA[128*128];
  __shared__ __align__(16) ushort lB[128*128];
  int tM = blockIdx.x, tN = blockIdx.y;
  int tid = threadIdx.x;
  int w = tid >> 6, l = tid & 63;

  // stage both 128x128 bf16 tiles (32 KB each) via async global->LDS, width 16
  {
    int rowgrp = tid >> 4;          // 0..15
    int cole = (tid & 15) * 8;      // element offset within row
    const ushort* gA = aB + (size_t)(tM*128) * 128;
    const ushort* gB = pB + (size_t)(tN*128) * 128;
    #pragma unroll
    for (int rnd = 0; rnd < 8; ++rnd) {
      int row = rnd*16 + rowgrp;
      g2l16(gA + (size_t)row*128 + cole, &lA[row*128 + cole]);
      g2l16(gB + (size_t)row*128 + cole, &lB[row*128 + cole]);
    }
  }
  __syncthreads();

  int wr = w >> 1, wc = w & 1;
  int lrow = l & 15, lk = (l >> 4) * 8;
  f32x4 acc[4][4] = {};
  #pragma unroll
  for (int ks = 0; ks < 4; ++ks) {
    bf16x8 aF[4], bF[4];
    #pragma unroll
    for (int m = 0; m < 4; ++m)
      aF[m] = *(const bf16x8*)&lA[(wr*64 + m*16 + lrow)*128 + ks*32 + lk];
    #pragma unroll
    for (int n = 0; n < 4; ++n)
      bF[n] = *(const bf16x8*)&lB[(wc*64 + n*16 + lrow)*128 + ks*32 + lk];
    #pragma unroll
    for (int m = 0; m < 4; ++m)
      #pragma unroll
      for (int n = 0; n < 4; ++n)
        acc[m][n] = __builtin_amdgcn_mfma_f32_16x16x32_bf16(aF[m], bF[n], acc[m][n], 0, 0, 0);
  }

  // epilogue: sq -> dm -> dmod -> row min; C/D map: col=l&15, row=(l>>4)*4+reg
  int rbase = (l >> 4) * 4;
  #pragma unroll
  for (int m = 0; m < 4; ++m) {
    int gi0 = tM*128 + wr*64 + m*16 + rbase;
    float d1v[4];
    #pragma unroll
    for (int reg = 0; reg < 4; ++reg) d1v[reg] = d1[gi0 + reg];
    float rmin[4] = {1e30f, 1e30f, 1e30f, 1e30f};
    #pragma unroll
    for (int n = 0; n < 4; ++n) {
      int gj = tN*128 + wc*64 + n*16 + (l & 15);
      float d2v = d2[gj];
      #pragma unroll
      for (int reg = 0; reg < 4; ++reg) {
        int gi = gi0 + reg;
        float sq = d1v[reg] + d2v - 2.0f * acc[m][n][reg];
        float dm = sqrtf(fmaxf(sq, 0.f) + 1e-6f) + 1e-8f;
        if (gi == gj) pos[gi] = dm;
        float dmod = dm + ((gi == gj) ? 10.f : 0.f);
        dmod += (dmod < 0.008f) ? 10.f : 0.f;
        rmin[reg] = fminf(rmin[reg], dmod);
      }
    }
    #pragma unroll
    for (int reg = 0; reg < 4; ++reg) {
      float v = rmin[reg];
      v = fminf(v, __shfl_xor(v, 1));
      v = fminf(v, __shfl_xor(v, 2));
      v = fminf(v, __shfl_xor(v, 4));
      v = fminf(v, __shfl_xor(v, 8));
      if ((l & 15) == 0) atomicMin(&mn[gi0 + reg], __float_as_uint(v));
    }
  }
}

// ---------------- finalize: mean(relu(margin + pos - min_neg)) ----------------
__global__ void fin_k(const float* __restrict__ pos, const unsigned* __restrict__ mn,
                      float* __restrict__ out) {
  float s = 0.f;
  for (int i = threadIdx.x; i < NPTS; i += 256) {
    float mneg = __uint_as_float(mn[i]);
    s += fmaxf(1.0f + pos[i] - mneg, 0.f);
  }
  for (int off = 1; off < 64; off <<= 1) s += __shfl_xor(s, off);
  __shared__ float red[4];
  if ((threadIdx.x & 63) == 0) red[threadIdx.x >> 6] = s;
  __syncthreads();
  if (threadIdx.x == 0) out[0] = (red[0] + red[1] + red[2] + red[3]) / (float)NPTS;
}

extern "C" void kernel_launch(void* const* d_in, const int* in_sizes, int n_in,
                              void* d_out, int out_size, void* d_ws, size_t ws_size,
                              hipStream_t stream) {
  const float* feat1 = (const float*)d_in[0];
  const float* feat2 = (const float*)d_in[1];
  const float* aflow = (const float*)d_in[2];

  char* ws = (char*)d_ws;
  ushort* aB = (ushort*)ws;                                   // NPAD*128 bf16
  ushort* pB = aB + (size_t)NPAD * 128;                       // NPAD*128 bf16
  float*  d1 = (float*)(pB + (size_t)NPAD * 128);             // NPAD f32
  float*  d2 = d1 + NPAD;
  float*  pos = d2 + NPAD;
  unsigned* mn = (unsigned*)(pos + NPAD);

  hipLaunchKernelGGL(init_k, dim3((NPAD + 255) / 256), dim3(256), 0, stream,
                     aB, pB, d1, d2, pos, mn);
  hipLaunchKernelGGL(sample_k, dim3(NPTS), dim3(128), 0, stream,
                     feat1, feat2, aflow, aB, pB, d1, d2);
  hipLaunchKernelGGL(gemm_k, dim3(NT, NT), dim3(256), 0, stream,
                     aB, pB, d1, d2, pos, mn);
  hipLaunchKernelGGL(fin_k, dim3(1), dim3(256), 0, stream,
                     pos, mn, (float*)d_out);
}

// Round 2
// 163.302 us; speedup vs baseline: 1.7735x; 1.7735x over previous
//
#include <hip/hip_runtime.h>
#include <stdint.h>

#define Hh 192
#define Ww 192
#define Cc 128
#define CROPW 38
#define CROPOFF 77
#define NPTS 11552    // 8*38*38
#define NPAD 11648    // 91*128
#define NT 91
#define BIGF 3.0e38f
#define SMALLSQ 6.2999998e-5f   // (0.008-1e-8)^2 - 1e-6 : dm<0.008 in sq-space

typedef short bf16x8 __attribute__((ext_vector_type(8)));
typedef float f32x4 __attribute__((ext_vector_type(4)));
typedef unsigned short ushort;

__device__ __forceinline__ ushort f2bf(float f) {
  uint32_t b = __float_as_uint(f);
  uint32_t r = b + 0x7fffu + ((b >> 16) & 1u);
  return (ushort)(r >> 16);
}

__device__ __forceinline__ void g2l16(const void* g, void* l) {
  __builtin_amdgcn_global_load_lds(
      (const __attribute__((address_space(1))) unsigned int*)g,
      (__attribute__((address_space(3))) unsigned int*)l, 16, 0, 0);
}

// ---------------- init: min_neg=+inf, pos=0, padding rows zeroed ----------------
__global__ void init_k(ushort* __restrict__ aB, ushort* __restrict__ pB,
                       float* __restrict__ d1, float* __restrict__ d2,
                       float* __restrict__ pos, unsigned* __restrict__ mn) {
  int i = blockIdx.x * 256 + threadIdx.x;
  if (i >= NPAD) return;
  mn[i] = 0x7f800000u;  // +inf
  pos[i] = 0.f;
  if (i >= NPTS) {
    d1[i] = 0.f;
    d2[i] = 1e30f;  // padded columns never win the min
    for (int c = 0; c < 128; ++c) { aB[(size_t)i*128 + c] = 0; pB[(size_t)i*128 + c] = 0; }
  }
}

// ---------------- sample + pack: bilinear gather of feat2, crop of feat1 --------
__global__ __launch_bounds__(128) void sample_k(
    const float* __restrict__ feat1, const float* __restrict__ feat2,
    const float* __restrict__ aflow,
    ushort* __restrict__ aB, ushort* __restrict__ pB,
    float* __restrict__ d1, float* __restrict__ d2) {
  int idx = blockIdx.x;                     // row order matches reference reshape
  int b = idx / (CROPW * CROPW);
  int rem = idx % (CROPW * CROPW);
  int r = rem / CROPW, cx = rem % CROPW;
  int y = CROPOFF + r, x = CROPOFF + cx;
  int c = threadIdx.x;                      // channel

  float ax = aflow[(((size_t)b*2 + 0)*Hh + y)*Ww + x];
  float ay = aflow[(((size_t)b*2 + 1)*Hh + y)*Ww + x];
  float gxn = ax * (2.0f/(Ww-1)) - 1.0f;
  float gyn = ay * (2.0f/(Hh-1)) - 1.0f;
  float gx = (gxn + 1.0f) * 0.5f * (Ww-1);
  float gy = (gyn + 1.0f) * 0.5f * (Hh-1);
  float x0 = floorf(gx), y0 = floorf(gy);
  float wx1 = gx - x0, wx0 = 1.f - wx1;
  float wy1 = gy - y0, wy0 = 1.f - wy1;

  const float* f2b = feat2 + ((size_t)b*Cc + c) * Hh * Ww;
  auto samp = [&](float xf, float yf) -> float {
    bool valid = (xf >= 0.f) && (xf <= (float)(Ww-1)) && (yf >= 0.f) && (yf <= (float)(Hh-1));
    int xi = (int)fminf(fmaxf(xf, 0.f), (float)(Ww-1));
    int yi = (int)fminf(fmaxf(yf, 0.f), (float)(Hh-1));
    float v = f2b[yi*Ww + xi];
    return valid ? v : 0.f;
  };
  float v = wx0*wy0*samp(x0,     y0    ) + wx1*wy0*samp(x0+1.f, y0    )
          + wx0*wy1*samp(x0,     y0+1.f) + wx1*wy1*samp(x0+1.f, y0+1.f);
  float f1v = feat1[((((size_t)b*Cc + c)*Hh) + y)*Ww + x];

  aB[(size_t)idx*128 + c] = f2bf(f1v);
  pB[(size_t)idx*128 + c] = f2bf(v);

  float s1 = f1v*f1v, s2 = v*v;
  for (int off = 1; off < 64; off <<= 1) { s1 += __shfl_xor(s1, off); s2 += __shfl_xor(s2, off); }
  __shared__ float red[4];
  if ((threadIdx.x & 63) == 0) { red[(threadIdx.x>>6)*2] = s1; red[(threadIdx.x>>6)*2+1] = s2; }
  __syncthreads();
  if (threadIdx.x == 0) { d1[idx] = red[0] + red[2]; d2[idx] = red[1] + red[3]; }
}

// ------------- fused GEMM + distance epilogue + row-min (swizzled LDS) ---------
// LDS layout: lds[row*256 + x] = global[row][x ^ ((row&7)<<4)] (byte offsets).
// global_load_lds dest stays linear (HW: base + lane*16); the SOURCE is
// pre-swizzled per-lane. Reads XOR the same pattern back.
// MFMA operands swapped: acc[np][ma] = mfma(bF, aF) so C "col" (lane&15) is the
// ANCHOR row -> row-min reduce is only xor16+xor32 across lanes.
template<bool DIAG>
__global__ __launch_bounds__(256) void gemm_k(
    const ushort* __restrict__ aB, const ushort* __restrict__ pB,
    const float* __restrict__ d1, const float* __restrict__ d2,
    float* __restrict__ pos, unsigned* __restrict__ mn) {
  __shared__ __align__(16) ushort lA[128*128];
  __shared__ __align__(16) ushort lB[128*128];
  int tM, tN;
  if (DIAG) { tM = blockIdx.x; tN = blockIdx.x; }
  else { tM = blockIdx.x; tN = blockIdx.y + (blockIdx.y >= blockIdx.x ? 1 : 0); }
  int tid = threadIdx.x;
  int w = tid >> 6, l = tid & 63;

  {
    int rowgrp = tid >> 4;              // 0..15
    int cb = (tid & 15) << 4;           // byte col within 256B row
    const char* gA = (const char*)(aB + (size_t)(tM*128) * 128);
    const char* gB = (const char*)(pB + (size_t)(tN*128) * 128);
    char* sA = (char*)lA; char* sB = (char*)lB;
    #pragma unroll
    for (int rnd = 0; rnd < 8; ++rnd) {
      int row = rnd*16 + rowgrp;
      int s = (row & 7) << 4;
      g2l16(gA + row*256 + (cb ^ s), sA + row*256 + cb);
      g2l16(gB + row*256 + (cb ^ s), sB + row*256 + cb);
    }
  }
  __syncthreads();

  int wr = w >> 1, wc = w & 1;
  int lcol = l & 15, hq = l >> 4;
  int rsw = (lcol & 7) << 4;            // read-side XOR (row&7 == lcol&7 here)
  f32x4 acc[4][4] = {};                 // acc[np][ma]
  #pragma unroll
  for (int ks = 0; ks < 4; ++ks) {
    bf16x8 aF[4], bF[4];
    int cbase = ks*64 + (hq << 4);      // byte k-offset within row
    #pragma unroll
    for (int ma = 0; ma < 4; ++ma)
      aF[ma] = *(const bf16x8*)((const char*)lA + (wr*64 + ma*16 + lcol)*256 + (cbase ^ rsw));
    #pragma unroll
    for (int np = 0; np < 4; ++np)
      bF[np] = *(const bf16x8*)((const char*)lB + (wc*64 + np*16 + lcol)*256 + (cbase ^ rsw));
    #pragma unroll
    for (int np = 0; np < 4; ++np)
      #pragma unroll
      for (int ma = 0; ma < 4; ++ma)
        acc[np][ma] = __builtin_amdgcn_mfma_f32_16x16x32_bf16(bF[np], aF[ma], acc[np][ma], 0, 0, 0);
  }

  // Epilogue in t-space: sq = d1(row) + t, t = d2(col) - 2*dot.
  // mU = min t over unmodified entries; mM = min t over (+10)-modified
  // (diag and dm<0.008); final min_neg = min(dm(mU), dm(mM)+10).
  int rb = hq << 2;
  f32x4 d2v[4];
  #pragma unroll
  for (int np = 0; np < 4; ++np)
    d2v[np] = *(const f32x4*)&d2[tN*128 + wc*64 + np*16 + rb];

  #pragma unroll
  for (int ma = 0; ma < 4; ++ma) {
    int gi = tM*128 + wr*64 + ma*16 + lcol;
    float d1v = d1[gi];
    float thr = SMALLSQ - d1v;
    float mU = BIGF, mM = BIGF, tD = BIGF;
    #pragma unroll
    for (int np = 0; np < 4; ++np) {
      #pragma unroll
      for (int reg = 0; reg < 4; ++reg) {
        float t = fmaf(-2.f, acc[np][ma][reg], d2v[np][reg]);
        bool excl = t < thr;
        if (DIAG) {
          bool isd = (wr == wc) && (ma == np) && (lcol == rb + reg);
          excl = excl || isd;
          tD = isd ? t : tD;
        }
        mU = fminf(mU, excl ? BIGF : t);
        mM = fminf(mM, excl ? t : BIGF);
      }
    }
    mU = fminf(mU, __shfl_xor(mU, 16));
    mU = fminf(mU, __shfl_xor(mU, 32));
    mM = fminf(mM, __shfl_xor(mM, 16));
    mM = fminf(mM, __shfl_xor(mM, 32));
    if (hq == 0) {
      float dmu = sqrtf(fmaxf(d1v + mU, 0.f) + 1e-6f) + 1e-8f;
      float dmm = sqrtf(fmaxf(d1v + mM, 0.f) + 1e-6f) + 1e-8f + 10.f;
      atomicMin(&mn[gi], __float_as_uint(fminf(dmu, dmm)));
    }
    if (DIAG) {
      if ((wr == wc) && ((lcol >> 2) == hq)) {
        float dmd = sqrtf(fmaxf(d1v + tD, 0.f) + 1e-6f) + 1e-8f;
        pos[gi] = dmd;
      }
    }
  }
}

// ---------------- finalize: mean(relu(margin + pos - min_neg)) ----------------
__global__ __launch_bounds__(1024) void fin_k(const float* __restrict__ pos,
                                              const unsigned* __restrict__ mn,
                                              float* __restrict__ out) {
  float s = 0.f;
  for (int i = threadIdx.x; i < NPTS; i += 1024) {
    float mneg = __uint_as_float(mn[i]);
    s += fmaxf(1.0f + pos[i] - mneg, 0.f);
  }
  for (int off = 1; off < 64; off <<= 1) s += __shfl_xor(s, off);
  __shared__ float red[16];
  if ((threadIdx.x & 63) == 0) red[threadIdx.x >> 6] = s;
  __syncthreads();
  if (threadIdx.x == 0) {
    float t = 0.f;
    #pragma unroll
    for (int k = 0; k < 16; ++k) t += red[k];
    out[0] = t / (float)NPTS;
  }
}

extern "C" void kernel_launch(void* const* d_in, const int* in_sizes, int n_in,
                              void* d_out, int out_size, void* d_ws, size_t ws_size,
                              hipStream_t stream) {
  const float* feat1 = (const float*)d_in[0];
  const float* feat2 = (const float*)d_in[1];
  const float* aflow = (const float*)d_in[2];

  char* ws = (char*)d_ws;
  ushort* aB = (ushort*)ws;                                   // NPAD*128 bf16
  ushort* pB = aB + (size_t)NPAD * 128;                       // NPAD*128 bf16
  float*  d1 = (float*)(pB + (size_t)NPAD * 128);             // NPAD f32
  float*  d2 = d1 + NPAD;
  float*  pos = d2 + NPAD;
  unsigned* mn = (unsigned*)(pos + NPAD);

  hipLaunchKernelGGL(init_k, dim3((NPAD + 255) / 256), dim3(256), 0, stream,
                     aB, pB, d1, d2, pos, mn);
  hipLaunchKernelGGL(sample_k, dim3(NPTS), dim3(128), 0, stream,
                     feat1, feat2, aflow, aB, pB, d1, d2);
  hipLaunchKernelGGL(gemm_k<true>, dim3(NT), dim3(256), 0, stream,
                     aB, pB, d1, d2, pos, mn);
  hipLaunchKernelGGL(gemm_k<false>, dim3(NT, NT - 1), dim3(256), 0, stream,
                     aB, pB, d1, d2, pos, mn);
  hipLaunchKernelGGL(fin_k, dim3(1), dim3(1024), 0, stream,
                     pos, mn, (float*)d_out);
}

// Round 3
// 133.377 us; speedup vs baseline: 2.1714x; 1.2244x over previous
//
#include <hip/hip_runtime.h>
#include <stdint.h>

#define Hh 192
#define Ww 192
#define CROPW 38
#define CROPOFF 77
#define NPTS 11552          // 8*38*38
#define NPAD 11776          // 46*256
#define NTT 46              // number of 256-row tiles
#define NOFF (NTT*(NTT-1))  // 2070 off-diagonal tiles
#define BIGF 3.0e38f

typedef short bf16x8 __attribute__((ext_vector_type(8)));
typedef float f32x4 __attribute__((ext_vector_type(4)));
typedef unsigned short ushort;

__device__ __forceinline__ ushort f2bf(float f) {
  uint32_t b = __float_as_uint(f);
  uint32_t r = b + 0x7fffu + ((b >> 16) & 1u);
  return (ushort)(r >> 16);
}

__device__ __forceinline__ void g2l16(const void* g, void* l) {
  __builtin_amdgcn_global_load_lds(
      (const __attribute__((address_space(1))) unsigned int*)g,
      (__attribute__((address_space(3))) unsigned int*)l, 16, 0, 0);
}

// ---------------- init: min_neg=+inf, pos=0, padding rows zeroed ----------------
__global__ void init_k(ushort* __restrict__ aB, ushort* __restrict__ pB,
                       float* __restrict__ d1, float* __restrict__ d2,
                       float* __restrict__ pos, unsigned* __restrict__ mn) {
  int i = blockIdx.x * 256 + threadIdx.x;
  if (i >= NPAD) return;
  mn[i] = 0x7f800000u;  // +inf
  pos[i] = 0.f;
  if (i >= NPTS) {
    d1[i] = 0.f;
    d2[i] = 1e30f;  // padded columns never win the min
    for (int c = 0; c < 128; ++c) { aB[(size_t)i*128 + c] = 0; pB[(size_t)i*128 + c] = 0; }
  }
}

// ---------------- sample + pack: bilinear gather of feat2, crop of feat1 --------
__global__ __launch_bounds__(128) void sample_k(
    const float* __restrict__ feat1, const float* __restrict__ feat2,
    const float* __restrict__ aflow,
    ushort* __restrict__ aB, ushort* __restrict__ pB,
    float* __restrict__ d1, float* __restrict__ d2) {
  int idx = blockIdx.x;                     // row order matches reference reshape
  int b = idx / (CROPW * CROPW);
  int rem = idx % (CROPW * CROPW);
  int r = rem / CROPW, cx = rem % CROPW;
  int y = CROPOFF + r, x = CROPOFF + cx;
  int c = threadIdx.x;                      // channel

  float ax = aflow[((b*2 + 0)*Hh + y)*Ww + x];
  float ay = aflow[((b*2 + 1)*Hh + y)*Ww + x];
  // replicate reference's normalize->denormalize round trip
  float gxn = ax * (2.0f/(Ww-1)) - 1.0f;
  float gyn = ay * (2.0f/(Hh-1)) - 1.0f;
  float gx = (gxn + 1.0f) * 0.5f * (Ww-1);
  float gy = (gyn + 1.0f) * 0.5f * (Hh-1);
  float x0 = floorf(gx), y0 = floorf(gy);
  float wx1 = gx - x0, wx0 = 1.f - wx1;
  float wy1 = gy - y0, wy0 = 1.f - wy1;

  // aflow in [0,191) => x0,y0 in [0,191]; only the +1 taps can fall off the edge.
  int xi = (int)x0, yi = (int)y0;
  bool xv = (xi < Ww - 1), yv = (yi < Hh - 1);
  const float* pl = feat2 + ((b*128 + c) * (Hh*Ww)) + yi*Ww + xi;
  float v00 = pl[0];
  float v01 = xv ? pl[1] : 0.f;
  float v10 = yv ? pl[Ww] : 0.f;
  float v11 = (xv && yv) ? pl[Ww + 1] : 0.f;
  float v = wy0*(wx0*v00 + wx1*v01) + wy1*(wx0*v10 + wx1*v11);
  float f1v = feat1[((b*128 + c)*Hh + y)*Ww + x];

  aB[(size_t)idx*128 + c] = f2bf(f1v);
  pB[(size_t)idx*128 + c] = f2bf(v);

  float s1 = f1v*f1v, s2 = v*v;
  for (int off = 1; off < 64; off <<= 1) { s1 += __shfl_xor(s1, off); s2 += __shfl_xor(s2, off); }
  __shared__ float red[4];
  if ((threadIdx.x & 63) == 0) { red[(threadIdx.x>>6)*2] = s1; red[(threadIdx.x>>6)*2+1] = s2; }
  __syncthreads();
  if (threadIdx.x == 0) { d1[idx] = red[0] + red[2]; d2[idx] = red[1] + red[3]; }
}

// ------ fused GEMM + distance epilogue + row-min, 256x256 tile / 8 waves -------
// LDS: lds[row*256 + x] = global[row][x ^ ((row&7)<<4)] (byte offsets); linear
// dest for global_load_lds, pre-swizzled SOURCE, XOR on read (both-sides rule).
// Swapped MFMA (mfma(bF,aF)): C "col" (lane&15) = anchor row; row-min reduce is
// xor16+xor32, then cross-wave combine via LDS scratch + ONE atomic per anchor.
template<bool DIAG>
__global__ __launch_bounds__(512, 2) void gemm_k(
    const ushort* __restrict__ aB, const ushort* __restrict__ pB,
    const float* __restrict__ d1, const float* __restrict__ d2,
    float* __restrict__ pos, unsigned* __restrict__ mn) {
  __shared__ __align__(16) ushort lA[256*128];   // 64 KB
  __shared__ __align__(16) ushort lB[256*128];   // 64 KB
  int tM, tN;
  if (DIAG) { tM = blockIdx.x; tN = blockIdx.x; }
  else {
    // chunked bijective XCD swizzle (m204): each XCD gets a contiguous L-range
    int bid = blockIdx.x;
    const int q = NOFF / 8, rr = NOFF % 8;        // 258, 6
    int xcd = bid & 7, ix = bid >> 3;
    int L = (xcd < rr ? xcd*(q+1) : rr*(q+1) + (xcd-rr)*q) + ix;
    tM = L % NTT;
    int yy = L / NTT;
    tN = yy + (yy >= tM ? 1 : 0);
  }
  int tid = threadIdx.x;

  {  // stage 256 rows x 256 B per matrix; 16 g2l16 per thread
    int rowg = tid >> 4;                // 0..31
    int cb = (tid & 15) << 4;           // byte col
    const char* gA = (const char*)aB + (size_t)tM * 65536;
    const char* gB = (const char*)pB + (size_t)tN * 65536;
    char* sA = (char*)lA; char* sB = (char*)lB;
    #pragma unroll
    for (int rnd = 0; rnd < 8; ++rnd) {
      int row = rnd*32 + rowg;
      int s = (row & 7) << 4;
      g2l16(gA + row*256 + (cb ^ s), sA + row*256 + cb);
      g2l16(gB + row*256 + (cb ^ s), sB + row*256 + cb);
    }
  }
  __syncthreads();

  int w = tid >> 6, l = tid & 63;
  int wr = w >> 2, wc = w & 3;          // wave tile: M 128 (wr) x N 64 (wc)
  int lcol = l & 15, hq = l >> 4;
  int rsw = (lcol & 7) << 4;
  f32x4 acc[4][8] = {};                 // acc[np][ma]
  #pragma unroll
  for (int ks = 0; ks < 4; ++ks) {
    bf16x8 aF[8], bF[4];
    int cbase = ks*64 + (hq << 4);
    #pragma unroll
    for (int ma = 0; ma < 8; ++ma)
      aF[ma] = *(const bf16x8*)((const char*)lA + (wr*128 + ma*16 + lcol)*256 + (cbase ^ rsw));
    #pragma unroll
    for (int np = 0; np < 4; ++np)
      bF[np] = *(const bf16x8*)((const char*)lB + (wc*64 + np*16 + lcol)*256 + (cbase ^ rsw));
    #pragma unroll
    for (int np = 0; np < 4; ++np)
      #pragma unroll
      for (int ma = 0; ma < 8; ++ma)
        acc[np][ma] = __builtin_amdgcn_mfma_f32_16x16x32_bf16(bF[np], aF[ma], acc[np][ma], 0, 0, 0);
  }

  // Epilogue in t-space: t = d2(col) - 2*dot; sq = d1(row) + t (sqrt deferred).
  int rb = hq << 2;
  f32x4 d2v[4];
  #pragma unroll
  for (int np = 0; np < 4; ++np)
    d2v[np] = *(const f32x4*)&d2[tN*256 + wc*64 + np*16 + rb];

  float mU[8];
  float mM[8];
  #pragma unroll
  for (int ma = 0; ma < 8; ++ma) {
    float u = BIGF, mm_ = BIGF;
    #pragma unroll
    for (int np = 0; np < 4; ++np) {
      #pragma unroll
      for (int reg = 0; reg < 4; ++reg) {
        float t = fmaf(-2.f, acc[np][ma][reg], d2v[np][reg]);
        if (DIAG) {
          int iloc = wr*128 + ma*16 + lcol;
          int jloc = wc*64 + np*16 + rb + reg;
          bool isd = (iloc == jloc);
          if (isd) {
            int gi = tM*256 + iloc;
            pos[gi] = sqrtf(fmaxf(d1[gi] + t, 0.f) + 1e-6f) + 1e-8f;
          }
          u = fminf(u, isd ? BIGF : t);
          mm_ = fminf(mm_, isd ? t : BIGF);
        } else {
          u = fminf(u, t);
        }
      }
    }
    u = fminf(u, __shfl_xor(u, 16));
    u = fminf(u, __shfl_xor(u, 32));
    mU[ma] = u;
    if (DIAG) {
      mm_ = fminf(mm_, __shfl_xor(mm_, 16));
      mm_ = fminf(mm_, __shfl_xor(mm_, 32));
      mM[ma] = mm_;
    }
  }

  // cross-wave combine: reuse lA/lB as scratch after all LDS reads are done
  __syncthreads();
  float* smU = (float*)lA;   // [4][256] by wc
  float* smM = (float*)lB;   // [4][256] (DIAG only)
  if (hq == 0) {
    #pragma unroll
    for (int ma = 0; ma < 8; ++ma) {
      int iloc = wr*128 + ma*16 + lcol;
      smU[wc*256 + iloc] = mU[ma];
      if (DIAG) smM[wc*256 + iloc] = mM[ma];
    }
  }
  __syncthreads();
  if (tid < 256) {
    int gi = tM*256 + tid;
    float u = fminf(fminf(smU[tid], smU[256 + tid]),
                    fminf(smU[512 + tid], smU[768 + tid]));
    float dv = d1[gi];
    float dmu = sqrtf(fmaxf(dv + u, 0.f) + 1e-6f) + 1e-8f;
    if (DIAG) {
      float m = fminf(fminf(smM[tid], smM[256 + tid]),
                      fminf(smM[512 + tid], smM[768 + tid]));
      float dmm = sqrtf(fmaxf(dv + m, 0.f) + 1e-6f) + 1e-8f + 10.f;
      dmu = fminf(dmu, dmm);
    }
    atomicMin(&mn[gi], __float_as_uint(dmu));
  }
}

// ---------------- finalize: mean(relu(margin + pos - min_neg)) ----------------
__global__ __launch_bounds__(1024) void fin_k(const float* __restrict__ pos,
                                              const unsigned* __restrict__ mn,
                                              float* __restrict__ out) {
  float s = 0.f;
  for (int i = threadIdx.x; i < NPTS; i += 1024) {
    float mneg = __uint_as_float(mn[i]);
    s += fmaxf(1.0f + pos[i] - mneg, 0.f);
  }
  for (int off = 1; off < 64; off <<= 1) s += __shfl_xor(s, off);
  __shared__ float red[16];
  if ((threadIdx.x & 63) == 0) red[threadIdx.x >> 6] = s;
  __syncthreads();
  if (threadIdx.x == 0) {
    float t = 0.f;
    #pragma unroll
    for (int k = 0; k < 16; ++k) t += red[k];
    out[0] = t / (float)NPTS;
  }
}

extern "C" void kernel_launch(void* const* d_in, const int* in_sizes, int n_in,
                              void* d_out, int out_size, void* d_ws, size_t ws_size,
                              hipStream_t stream) {
  const float* feat1 = (const float*)d_in[0];
  const float* feat2 = (const float*)d_in[1];
  const float* aflow = (const float*)d_in[2];

  char* ws = (char*)d_ws;
  ushort* aB = (ushort*)ws;                                   // NPAD*128 bf16
  ushort* pB = aB + (size_t)NPAD * 128;                       // NPAD*128 bf16
  float*  d1 = (float*)(pB + (size_t)NPAD * 128);             // NPAD f32
  float*  d2 = d1 + NPAD;
  float*  pos = d2 + NPAD;
  unsigned* mn = (unsigned*)(pos + NPAD);

  hipLaunchKernelGGL(init_k, dim3((NPAD + 255) / 256), dim3(256), 0, stream,
                     aB, pB, d1, d2, pos, mn);
  hipLaunchKernelGGL(sample_k, dim3(NPTS), dim3(128), 0, stream,
                     feat1, feat2, aflow, aB, pB, d1, d2);
  hipLaunchKernelGGL(gemm_k<true>, dim3(NTT), dim3(512), 0, stream,
                     aB, pB, d1, d2, pos, mn);
  hipLaunchKernelGGL(gemm_k<false>, dim3(NOFF), dim3(512), 0, stream,
                     aB, pB, d1, d2, pos, mn);
  hipLaunchKernelGGL(fin_k, dim3(1), dim3(1024), 0, stream,
                     pos, mn, (float*)d_out);
}

// Round 4
// 124.335 us; speedup vs baseline: 2.3293x; 1.0727x over previous
//
#include <hip/hip_runtime.h>
#include <stdint.h>

#define Hh 192
#define Ww 192
#define CROPW 38
#define CROPOFF 77
#define NPTS 11552          // 8*38*38
#define NPAD 11776          // 46*256
#define NTT 46              // 256-row tiles
#define NCT 92              // 128-col tiles
#define NG 5                // col-tile groups
#define JPB 19              // col-tiles per group (last group gets 16)
#define NBLK (NG*NTT)       // 230 persistent blocks
#define BIGF 3.0e38f

typedef short bf16x8 __attribute__((ext_vector_type(8)));
typedef float f32x4 __attribute__((ext_vector_type(4)));
typedef int   i32x4 __attribute__((ext_vector_type(4)));
typedef unsigned short ushort;

__device__ __forceinline__ ushort f2bf(float f) {
  uint32_t b = __float_as_uint(f);
  uint32_t r = b + 0x7fffu + ((b >> 16) & 1u);
  return (ushort)(r >> 16);
}

__device__ __forceinline__ void g2l16(const void* g, void* l) {
  __builtin_amdgcn_global_load_lds(
      (const __attribute__((address_space(1))) unsigned int*)g,
      (__attribute__((address_space(3))) unsigned int*)l, 16, 0, 0);
}

// ---------------- init: pad rows of aB/pB zeroed, d1/d2 padding ----------------
__global__ void init_k(ushort* __restrict__ aB, ushort* __restrict__ pB,
                       float* __restrict__ d1, float* __restrict__ d2) {
  int i = blockIdx.x * 256 + threadIdx.x;
  if (i < NPTS || i >= NPAD) return;
  d1[i] = 0.f;
  d2[i] = 1e30f;  // padded columns never win the min
  i32x4 z = {0,0,0,0};
  #pragma unroll
  for (int c = 0; c < 16; ++c) {
    *(i32x4*)&aB[(size_t)i*128 + c*8] = z;
    *(i32x4*)&pB[(size_t)i*128 + c*8] = z;
  }
}

// ---------------- sample + pack: bilinear gather of feat2, crop of feat1 --------
__global__ __launch_bounds__(128) void sample_k(
    const float* __restrict__ feat1, const float* __restrict__ feat2,
    const float* __restrict__ aflow,
    ushort* __restrict__ aB, ushort* __restrict__ pB,
    float* __restrict__ d1, float* __restrict__ d2) {
  int idx = blockIdx.x;                     // row order matches reference reshape
  int b = idx / (CROPW * CROPW);
  int rem = idx % (CROPW * CROPW);
  int r = rem / CROPW, cx = rem % CROPW;
  int y = CROPOFF + r, x = CROPOFF + cx;
  int c = threadIdx.x;                      // channel

  float ax = aflow[((b*2 + 0)*Hh + y)*Ww + x];
  float ay = aflow[((b*2 + 1)*Hh + y)*Ww + x];
  float gxn = ax * (2.0f/(Ww-1)) - 1.0f;
  float gyn = ay * (2.0f/(Hh-1)) - 1.0f;
  float gx = (gxn + 1.0f) * 0.5f * (Ww-1);
  float gy = (gyn + 1.0f) * 0.5f * (Hh-1);
  float x0 = floorf(gx), y0 = floorf(gy);
  float wx1 = gx - x0, wx0 = 1.f - wx1;
  float wy1 = gy - y0, wy0 = 1.f - wy1;

  int xi = (int)x0, yi = (int)y0;
  bool xv = (xi < Ww - 1), yv = (yi < Hh - 1);
  const float* pl = feat2 + ((b*128 + c) * (Hh*Ww)) + yi*Ww + xi;
  float v00 = pl[0];
  float v01 = xv ? pl[1] : 0.f;
  float v10 = yv ? pl[Ww] : 0.f;
  float v11 = (xv && yv) ? pl[Ww + 1] : 0.f;
  float v = wy0*(wx0*v00 + wx1*v01) + wy1*(wx0*v10 + wx1*v11);
  float f1v = feat1[((b*128 + c)*Hh + y)*Ww + x];

  aB[(size_t)idx*128 + c] = f2bf(f1v);
  pB[(size_t)idx*128 + c] = f2bf(v);

  float s1 = f1v*f1v, s2 = v*v;
  for (int off = 1; off < 64; off <<= 1) { s1 += __shfl_xor(s1, off); s2 += __shfl_xor(s2, off); }
  __shared__ float red[4];
  if ((threadIdx.x & 63) == 0) { red[(threadIdx.x>>6)*2] = s1; red[(threadIdx.x>>6)*2+1] = s2; }
  __syncthreads();
  if (threadIdx.x == 0) { d1[idx] = red[0] + red[2]; d2[idx] = red[1] + red[3]; }
}

// ---- persistent fused GEMM: A-resident, B double-buffered 2-phase pipeline ----
// Block = (g, tM): A tile (256 rows, 64KB) staged once; loop over ~19 B col-tiles
// (128 cols, 32KB) with prefetch-next-into-alt-buffer before compute (T3 min).
// Swizzle: lds[row*256 + x] = g[row][x ^ ((row&7)<<4)] (linear dest, pre-swizzled
// source, XOR on read). Swapped MFMA: anchor index lands in lane&15.
// Row-mins accumulate in REGISTERS (t-space) across iters; no atomics:
// per-group partial dm written to pmin[g][row], reduced in fin_k.
__global__ __launch_bounds__(512) void gemmp_k(
    const ushort* __restrict__ aB, const ushort* __restrict__ pB,
    const float* __restrict__ d1, const float* __restrict__ d2,
    float* __restrict__ pos, float* __restrict__ pmin) {
  __shared__ __align__(16) ushort lA[256*128];      // 64 KB
  __shared__ __align__(16) ushort lB[2][128*128];   // 2 x 32 KB

  // m204 bijective chunked XCD swizzle: nwg=230, q=28, r=6
  int bid = blockIdx.x;
  int xcd = bid & 7, k = bid >> 3;
  int start = (xcd < 6) ? xcd*29 : 174 + (xcd-6)*28;
  int L = start + k;
  int g = L / NTT, tM = L % NTT;
  int j0 = g * JPB;
  int jn = (NCT - j0 < JPB) ? (NCT - j0) : JPB;

  int tid = threadIdx.x;
  int rowg = tid >> 4, cb = (tid & 15) << 4;

  {  // stage A once: 256 rows x 256 B
    const char* gA = (const char*)aB + (size_t)tM * 65536;
    #pragma unroll
    for (int rnd = 0; rnd < 8; ++rnd) {
      int row = rnd*32 + rowg;
      g2l16(gA + row*256 + (cb ^ ((row&7)<<4)), (char*)lA + row*256 + cb);
    }
  }
  {  // stage B0
    const char* gB = (const char*)pB + (size_t)j0 * 128 * 256;
    #pragma unroll
    for (int rnd = 0; rnd < 4; ++rnd) {
      int row = rnd*32 + rowg;
      g2l16(gB + row*256 + (cb ^ ((row&7)<<4)), (char*)lB[0] + row*256 + cb);
    }
  }
  __syncthreads();   // drains vmcnt

  int w = tid >> 6, l = tid & 63;
  int wr = w >> 1, wc = w & 1;          // 4M x 2N waves; wave tile 64x64
  int lcol = l & 15, hq = l >> 4, rb = hq << 2;
  int rsw = (lcol & 7) << 4;
  float mPart[4] = {BIGF, BIGF, BIGF, BIGF};

  for (int it = 0; it < jn; ++it) {
    int j = j0 + it;
    if (it + 1 < jn) {  // prefetch next B into alt buffer (overlaps compute)
      const char* gB = (const char*)pB + (size_t)(j+1) * 128 * 256;
      char* dst = (char*)lB[(it+1) & 1];
      #pragma unroll
      for (int rnd = 0; rnd < 4; ++rnd) {
        int row = rnd*32 + rowg;
        g2l16(gB + row*256 + (cb ^ ((row&7)<<4)), dst + row*256 + cb);
      }
    }
    const char* bufB = (const char*)lB[it & 1];
    f32x4 acc[4][4] = {};               // acc[np][ma]
    #pragma unroll
    for (int ks = 0; ks < 4; ++ks) {
      int cbase = ks*64 + (hq << 4);
      bf16x8 aF[4], bF[4];
      #pragma unroll
      for (int ma = 0; ma < 4; ++ma)
        aF[ma] = *(const bf16x8*)((const char*)lA + (wr*64 + ma*16 + lcol)*256 + (cbase ^ rsw));
      #pragma unroll
      for (int np = 0; np < 4; ++np)
        bF[np] = *(const bf16x8*)(bufB + (wc*64 + np*16 + lcol)*256 + (cbase ^ rsw));
      #pragma unroll
      for (int np = 0; np < 4; ++np)
        #pragma unroll
        for (int ma = 0; ma < 4; ++ma)
          acc[np][ma] = __builtin_amdgcn_mfma_f32_16x16x32_bf16(bF[np], aF[ma], acc[np][ma], 0, 0, 0);
    }

    // epilogue in t-space: t = d2[col] - 2*dot; min accumulates in mPart regs
    f32x4 d2v[4];
    #pragma unroll
    for (int np = 0; np < 4; ++np)
      d2v[np] = *(const f32x4*)&d2[j*128 + wc*64 + np*16 + rb];

    if ((j >> 1) != tM) {               // non-diagonal col-tile (uniform branch)
      #pragma unroll
      for (int ma = 0; ma < 4; ++ma)
        #pragma unroll
        for (int np = 0; np < 4; ++np)
          #pragma unroll
          for (int reg = 0; reg < 4; ++reg)
            mPart[ma] = fminf(mPart[ma], fmaf(-2.f, acc[np][ma][reg], d2v[np][reg]));
    } else {                            // diagonal-overlapping tile
      #pragma unroll
      for (int ma = 0; ma < 4; ++ma) {
        int gi = tM*256 + wr*64 + ma*16 + lcol;
        #pragma unroll
        for (int np = 0; np < 4; ++np)
          #pragma unroll
          for (int reg = 0; reg < 4; ++reg) {
            int gj = j*128 + wc*64 + np*16 + rb + reg;
            float t = fmaf(-2.f, acc[np][ma][reg], d2v[np][reg]);
            if (gi == gj)
              pos[gi] = sqrtf(fmaxf(d1[gi] + t, 0.f) + 1e-6f) + 1e-8f;
            else
              mPart[ma] = fminf(mPart[ma], t);
          }
      }
    }
    __syncthreads();                    // next buffer staged + all reads done
  }

  // final reduce: over hq via shuffles, over wc via LDS scratch; non-atomic store
  #pragma unroll
  for (int ma = 0; ma < 4; ++ma) {
    float u = mPart[ma];
    u = fminf(u, __shfl_xor(u, 16));
    u = fminf(u, __shfl_xor(u, 32));
    mPart[ma] = u;
  }
  __syncthreads();
  float* sm = (float*)lB;               // scratch [2][256]
  if (hq == 0) {
    #pragma unroll
    for (int ma = 0; ma < 4; ++ma)
      sm[wc*256 + wr*64 + ma*16 + lcol] = mPart[ma];
  }
  __syncthreads();
  if (tid < 256) {
    int row = tM*256 + tid;
    float u = fminf(sm[tid], sm[256 + tid]);
    float dm = sqrtf(fmaxf(d1[row] + u, 0.f) + 1e-6f) + 1e-8f;
    pmin[g*NPAD + row] = dm;
  }
}

// -------- finalize: min over group partials (+ diag+10 cand), mean relu --------
__global__ __launch_bounds__(1024) void fin_k(const float* __restrict__ pos,
                                              const float* __restrict__ pmin,
                                              float* __restrict__ out) {
  float s = 0.f;
  for (int i = threadIdx.x; i < NPTS; i += 1024) {
    float p = pos[i];
    float mneg = p + 10.f;              // diagonal's +10-modified candidate
    #pragma unroll
    for (int g = 0; g < NG; ++g) mneg = fminf(mneg, pmin[g*NPAD + i]);
    s += fmaxf(1.0f + p - mneg, 0.f);
  }
  for (int off = 1; off < 64; off <<= 1) s += __shfl_xor(s, off);
  __shared__ float red[16];
  if ((threadIdx.x & 63) == 0) red[threadIdx.x >> 6] = s;
  __syncthreads();
  if (threadIdx.x == 0) {
    float t = 0.f;
    #pragma unroll
    for (int k = 0; k < 16; ++k) t += red[k];
    out[0] = t / (float)NPTS;
  }
}

extern "C" void kernel_launch(void* const* d_in, const int* in_sizes, int n_in,
                              void* d_out, int out_size, void* d_ws, size_t ws_size,
                              hipStream_t stream) {
  const float* feat1 = (const float*)d_in[0];
  const float* feat2 = (const float*)d_in[1];
  const float* aflow = (const float*)d_in[2];

  char* ws = (char*)d_ws;
  ushort* aB = (ushort*)ws;                                   // NPAD*128 bf16
  ushort* pB = aB + (size_t)NPAD * 128;                       // NPAD*128 bf16
  float*  d1 = (float*)(pB + (size_t)NPAD * 128);             // NPAD f32
  float*  d2 = d1 + NPAD;
  float*  pos = d2 + NPAD;
  float*  pmin = pos + NPAD;                                  // NG*NPAD f32

  hipLaunchKernelGGL(init_k, dim3((NPAD + 255) / 256), dim3(256), 0, stream,
                     aB, pB, d1, d2);
  hipLaunchKernelGGL(sample_k, dim3(NPTS), dim3(128), 0, stream,
                     feat1, feat2, aflow, aB, pB, d1, d2);
  hipLaunchKernelGGL(gemmp_k, dim3(NBLK), dim3(512), 0, stream,
                     aB, pB, d1, d2, pos, pmin);
  hipLaunchKernelGGL(fin_k, dim3(1), dim3(1024), 0, stream,
                     pos, pmin, (float*)d_out);
}

// Round 5
// 107.231 us; speedup vs baseline: 2.7009x; 1.1595x over previous
//
#include <hip/hip_runtime.h>
#include <stdint.h>

#define Hh 192
#define Ww 192
#define HW 36864            // 192*192
#define CROPW 38
#define CW2 1444            // 38*38
#define CROPOFF 77
#define NPTS 11552          // 8*38*38
#define NPAD 11776          // 46*256
#define NTT 46              // 256-row tiles
#define NCT 92              // 128-col tiles
#define NG 5                // col-tile groups
#define JPB 19              // col-tiles per group (last group gets 16)
#define NBLK (NG*NTT)       // 230 persistent blocks
#define BIGF 3.0e38f

typedef short bf16x8 __attribute__((ext_vector_type(8)));
typedef float f32x4 __attribute__((ext_vector_type(4)));
typedef int   i32x4 __attribute__((ext_vector_type(4)));
typedef unsigned short ushort;

__device__ __forceinline__ ushort f2bf(float f) {
  uint32_t b = __float_as_uint(f);
  uint32_t r = b + 0x7fffu + ((b >> 16) & 1u);
  return (ushort)(r >> 16);
}
__device__ __forceinline__ float bf2f(ushort u) {
  return __uint_as_float(((uint32_t)u) << 16);
}

__device__ __forceinline__ void g2l16(const void* g, void* l) {
  __builtin_amdgcn_global_load_lds(
      (const __attribute__((address_space(1))) unsigned int*)g,
      (__attribute__((address_space(3))) unsigned int*)l, 16, 0, 0);
}

// ---------------- init: pad rows of aB/pB zeroed, d1/d2 padding ----------------
__global__ void init_k(ushort* __restrict__ aB, ushort* __restrict__ pB,
                       float* __restrict__ d1, float* __restrict__ d2) {
  int i = NPTS + threadIdx.x;
  if (i >= NPAD) return;
  d1[i] = 0.f;
  d2[i] = 1e30f;  // padded columns never win the min
  i32x4 z = {0,0,0,0};
  #pragma unroll
  for (int c = 0; c < 16; ++c) {
    *(i32x4*)&aB[(size_t)i*128 + c*8] = z;
    *(i32x4*)&pB[(size_t)i*128 + c*8] = z;
  }
}

// ------- transpose feat2 (B,C,H,W) f32 -> f2t (B,H,W,C) bf16, LDS-tiled -------
// tile: 32 hw-positions x 128 channels. Read coalesced along hw (float4/lane),
// write coalesced along c (32B/lane). LDS row padded to 136 ushorts (16B-mult,
// bank stride 68 dwords => ~2-way conflicts).
__global__ __launch_bounds__(256) void transpose_k(
    const float* __restrict__ feat2, ushort* __restrict__ f2t) {
  __shared__ __align__(16) ushort l[32*136];
  int b = blockIdx.y;
  int hw0 = blockIdx.x * 32;
  int t = threadIdx.x;
  {
    int i4 = (t & 7) * 4, c0 = t >> 3;           // 8 lanes cover 32 hw, 32 c/wave
    const float* src = feat2 + (size_t)b*128*HW + hw0 + i4;
    #pragma unroll
    for (int k = 0; k < 4; ++k) {
      int cc = c0 + k*32;
      f32x4 v = *(const f32x4*)(src + (size_t)cc*HW);
      #pragma unroll
      for (int j = 0; j < 4; ++j) l[(i4+j)*136 + cc] = f2bf(v[j]);
    }
  }
  __syncthreads();
  {
    int chunk = t & 7, p = t >> 3;               // chunk fast => contiguous global
    ushort* dst = f2t + ((size_t)b*HW + hw0 + p)*128 + chunk*16;
    *(bf16x8*)dst       = *(const bf16x8*)&l[p*136 + chunk*16];
    *(bf16x8*)(dst + 8) = *(const bf16x8*)&l[p*136 + chunk*16 + 8];
  }
}

// ------ crop feat1 (38x38 region) -> aB (bf16 channel-last) + d1 norms --------
__global__ __launch_bounds__(256) void crop_k(
    const float* __restrict__ feat1, ushort* __restrict__ aB,
    float* __restrict__ d1) {
  __shared__ __align__(16) ushort l[38*136];
  int r = blockIdx.x;                // 0..37 (y = 77+r)
  int b = blockIdx.y;
  int y = CROPOFF + r;
  int t = threadIdx.x;
  {
    int xo = t & 63, c0 = t >> 6;    // 38 active lanes, 32 c per wave-loop
    if (xo < CROPW) {
      const float* src = feat1 + ((size_t)b*128*HW) + (size_t)y*Ww + CROPOFF + xo;
      #pragma unroll
      for (int k = 0; k < 32; ++k) {
        int cc = c0*32 + k;
        l[xo*136 + cc] = f2bf(src[(size_t)cc*HW]);
      }
    }
  }
  __syncthreads();
  int chunk = t & 7, p0 = t >> 3;
  #pragma unroll
  for (int pp = 0; pp < 2; ++pp) {
    int p = p0 + pp*32;
    if (p >= CROPW) break;
    int idx = b*CW2 + r*CROPW + p;
    ushort* dst = aB + (size_t)idx*128 + chunk*16;
    *(bf16x8*)dst       = *(const bf16x8*)&l[p*136 + chunk*16];
    *(bf16x8*)(dst + 8) = *(const bf16x8*)&l[p*136 + chunk*16 + 8];
    float s = 0.f;
    #pragma unroll
    for (int j = 0; j < 16; ++j) {
      float v = bf2f(l[p*136 + chunk*16 + j]);
      s += v*v;
    }
    s += __shfl_xor(s, 1); s += __shfl_xor(s, 2); s += __shfl_xor(s, 4);
    if (chunk == 0) d1[idx] = s;
  }
}

// ---- sample: coalesced bilinear from f2t (channel-last bf16) -> pB + d2 ------
// 2 points per block (128 threads each, lane = channel).
__global__ __launch_bounds__(256) void samp2_k(
    const ushort* __restrict__ f2t, const float* __restrict__ aflow,
    ushort* __restrict__ pB, float* __restrict__ d2) {
  int tid = threadIdx.x;
  int idx = blockIdx.x*2 + (tid >> 7);
  int c = tid & 127;
  int b = idx / CW2;
  int rem = idx % CW2;
  int r = rem / CROPW, cx = rem % CROPW;
  int y = CROPOFF + r, x = CROPOFF + cx;

  float ax = aflow[((b*2 + 0)*Hh + y)*Ww + x];
  float ay = aflow[((b*2 + 1)*Hh + y)*Ww + x];
  // replicate reference's normalize->denormalize round trip
  float gxn = ax * (2.0f/(Ww-1)) - 1.0f;
  float gyn = ay * (2.0f/(Hh-1)) - 1.0f;
  float gx = (gxn + 1.0f) * 0.5f * (Ww-1);
  float gy = (gyn + 1.0f) * 0.5f * (Hh-1);
  // clamp base cell to 190: when gx==191 exactly, weights shift to the x=191
  // tap with weight 1 (identical result, no OOB read).
  int xi = min((int)floorf(gx), Ww-2);
  int yi = min((int)floorf(gy), Hh-2);
  float wx1 = gx - (float)xi, wx0 = 1.f - wx1;
  float wy1 = gy - (float)yi, wy0 = 1.f - wy1;

  const ushort* base = f2t + ((size_t)b*HW + (size_t)yi*Ww + xi)*128 + c;
  float v00 = bf2f(base[0]);
  float v01 = bf2f(base[128]);
  float v10 = bf2f(base[Ww*128]);
  float v11 = bf2f(base[Ww*128 + 128]);
  float v = wy0*(wx0*v00 + wx1*v01) + wy1*(wx0*v10 + wx1*v11);

  pB[(size_t)idx*128 + c] = f2bf(v);

  float s = v*v;
  for (int off = 1; off < 64; off <<= 1) s += __shfl_xor(s, off);
  __shared__ float red[4];
  if ((tid & 63) == 0) red[tid >> 6] = s;
  __syncthreads();
  if ((tid & 127) == 0) {
    int g = tid >> 7;
    d2[idx] = red[2*g] + red[2*g + 1];
  }
}

// ---- persistent fused GEMM: A-resident, B double-buffered 2-phase pipeline ----
__global__ __launch_bounds__(512) void gemmp_k(
    const ushort* __restrict__ aB, const ushort* __restrict__ pB,
    const float* __restrict__ d1, const float* __restrict__ d2,
    float* __restrict__ pos, float* __restrict__ pmin) {
  __shared__ __align__(16) ushort lA[256*128];      // 64 KB
  __shared__ __align__(16) ushort lB[2][128*128];   // 2 x 32 KB

  // m204 bijective chunked XCD swizzle: nwg=230, q=28, r=6
  int bid = blockIdx.x;
  int xcd = bid & 7, k = bid >> 3;
  int start = (xcd < 6) ? xcd*29 : 174 + (xcd-6)*28;
  int L = start + k;
  int g = L / NTT, tM = L % NTT;
  int j0 = g * JPB;
  int jn = (NCT - j0 < JPB) ? (NCT - j0) : JPB;

  int tid = threadIdx.x;
  int rowg = tid >> 4, cb = (tid & 15) << 4;

  {  // stage A once: 256 rows x 256 B
    const char* gA = (const char*)aB + (size_t)tM * 65536;
    #pragma unroll
    for (int rnd = 0; rnd < 8; ++rnd) {
      int row = rnd*32 + rowg;
      g2l16(gA + row*256 + (cb ^ ((row&7)<<4)), (char*)lA + row*256 + cb);
    }
  }
  {  // stage B0
    const char* gB = (const char*)pB + (size_t)j0 * 128 * 256;
    #pragma unroll
    for (int rnd = 0; rnd < 4; ++rnd) {
      int row = rnd*32 + rowg;
      g2l16(gB + row*256 + (cb ^ ((row&7)<<4)), (char*)lB[0] + row*256 + cb);
    }
  }
  __syncthreads();   // drains vmcnt

  int w = tid >> 6, l = tid & 63;
  int wr = w >> 1, wc = w & 1;          // 4M x 2N waves; wave tile 64x64
  int lcol = l & 15, hq = l >> 4, rb = hq << 2;
  int rsw = (lcol & 7) << 4;
  float mPart[4] = {BIGF, BIGF, BIGF, BIGF};

  for (int it = 0; it < jn; ++it) {
    int j = j0 + it;
    if (it + 1 < jn) {  // prefetch next B into alt buffer (overlaps compute)
      const char* gB = (const char*)pB + (size_t)(j+1) * 128 * 256;
      char* dst = (char*)lB[(it+1) & 1];
      #pragma unroll
      for (int rnd = 0; rnd < 4; ++rnd) {
        int row = rnd*32 + rowg;
        g2l16(gB + row*256 + (cb ^ ((row&7)<<4)), dst + row*256 + cb);
      }
    }
    const char* bufB = (const char*)lB[it & 1];
    f32x4 acc[4][4] = {};               // acc[np][ma]
    #pragma unroll
    for (int ks = 0; ks < 4; ++ks) {
      int cbase = ks*64 + (hq << 4);
      bf16x8 aF[4], bF[4];
      #pragma unroll
      for (int ma = 0; ma < 4; ++ma)
        aF[ma] = *(const bf16x8*)((const char*)lA + (wr*64 + ma*16 + lcol)*256 + (cbase ^ rsw));
      #pragma unroll
      for (int np = 0; np < 4; ++np)
        bF[np] = *(const bf16x8*)(bufB + (wc*64 + np*16 + lcol)*256 + (cbase ^ rsw));
      #pragma unroll
      for (int np = 0; np < 4; ++np)
        #pragma unroll
        for (int ma = 0; ma < 4; ++ma)
          acc[np][ma] = __builtin_amdgcn_mfma_f32_16x16x32_bf16(bF[np], aF[ma], acc[np][ma], 0, 0, 0);
    }

    // epilogue in t-space: t = d2[col] - 2*dot; min accumulates in mPart regs
    f32x4 d2v[4];
    #pragma unroll
    for (int np = 0; np < 4; ++np)
      d2v[np] = *(const f32x4*)&d2[j*128 + wc*64 + np*16 + rb];

    if ((j >> 1) != tM) {               // non-diagonal col-tile (uniform branch)
      #pragma unroll
      for (int ma = 0; ma < 4; ++ma)
        #pragma unroll
        for (int np = 0; np < 4; ++np)
          #pragma unroll
          for (int reg = 0; reg < 4; ++reg)
            mPart[ma] = fminf(mPart[ma], fmaf(-2.f, acc[np][ma][reg], d2v[np][reg]));
    } else {                            // diagonal-overlapping tile
      #pragma unroll
      for (int ma = 0; ma < 4; ++ma) {
        int gi = tM*256 + wr*64 + ma*16 + lcol;
        #pragma unroll
        for (int np = 0; np < 4; ++np)
          #pragma unroll
          for (int reg = 0; reg < 4; ++reg) {
            int gj = j*128 + wc*64 + np*16 + rb + reg;
            float t = fmaf(-2.f, acc[np][ma][reg], d2v[np][reg]);
            if (gi == gj)
              pos[gi] = sqrtf(fmaxf(d1[gi] + t, 0.f) + 1e-6f) + 1e-8f;
            else
              mPart[ma] = fminf(mPart[ma], t);
          }
      }
    }
    __syncthreads();                    // next buffer staged + all reads done
  }

  // final reduce: over hq via shuffles, over wc via LDS scratch; non-atomic store
  #pragma unroll
  for (int ma = 0; ma < 4; ++ma) {
    float u = mPart[ma];
    u = fminf(u, __shfl_xor(u, 16));
    u = fminf(u, __shfl_xor(u, 32));
    mPart[ma] = u;
  }
  __syncthreads();
  float* sm = (float*)lB;               // scratch [2][256]
  if (hq == 0) {
    #pragma unroll
    for (int ma = 0; ma < 4; ++ma)
      sm[wc*256 + wr*64 + ma*16 + lcol] = mPart[ma];
  }
  __syncthreads();
  if (tid < 256) {
    int row = tM*256 + tid;
    float u = fminf(sm[tid], sm[256 + tid]);
    float dm = sqrtf(fmaxf(d1[row] + u, 0.f) + 1e-6f) + 1e-8f;
    pmin[g*NPAD + row] = dm;
  }
}

// -------- finalize: min over group partials (+ diag+10 cand), mean relu --------
__global__ __launch_bounds__(1024) void fin_k(const float* __restrict__ pos,
                                              const float* __restrict__ pmin,
                                              float* __restrict__ out) {
  float s = 0.f;
  for (int i = threadIdx.x; i < NPTS; i += 1024) {
    float p = pos[i];
    float mneg = p + 10.f;              // diagonal's +10-modified candidate
    #pragma unroll
    for (int g = 0; g < NG; ++g) mneg = fminf(mneg, pmin[g*NPAD + i]);
    s += fmaxf(1.0f + p - mneg, 0.f);
  }
  for (int off = 1; off < 64; off <<= 1) s += __shfl_xor(s, off);
  __shared__ float red[16];
  if ((threadIdx.x & 63) == 0) red[threadIdx.x >> 6] = s;
  __syncthreads();
  if (threadIdx.x == 0) {
    float t = 0.f;
    #pragma unroll
    for (int k = 0; k < 16; ++k) t += red[k];
    out[0] = t / (float)NPTS;
  }
}

extern "C" void kernel_launch(void* const* d_in, const int* in_sizes, int n_in,
                              void* d_out, int out_size, void* d_ws, size_t ws_size,
                              hipStream_t stream) {
  const float* feat1 = (const float*)d_in[0];
  const float* feat2 = (const float*)d_in[1];
  const float* aflow = (const float*)d_in[2];

  char* ws = (char*)d_ws;
  ushort* aB = (ushort*)ws;                                   // NPAD*128 bf16
  ushort* pB = aB + (size_t)NPAD * 128;                       // NPAD*128 bf16
  float*  d1 = (float*)(pB + (size_t)NPAD * 128);             // NPAD f32
  float*  d2 = d1 + NPAD;
  float*  pos = d2 + NPAD;
  float*  pmin = pos + NPAD;                                  // NG*NPAD f32
  ushort* f2t = (ushort*)(pmin + (size_t)NG*NPAD);            // 8*HW*128 bf16

  hipLaunchKernelGGL(transpose_k, dim3(HW/32, 8), dim3(256), 0, stream,
                     feat2, f2t);
  hipLaunchKernelGGL(init_k, dim3(1), dim3(256), 0, stream,
                     aB, pB, d1, d2);
  hipLaunchKernelGGL(crop_k, dim3(CROPW, 8), dim3(256), 0, stream,
                     feat1, aB, d1);
  hipLaunchKernelGGL(samp2_k, dim3(NPTS/2), dim3(256), 0, stream,
                     f2t, aflow, pB, d2);
  hipLaunchKernelGGL(gemmp_k, dim3(NBLK), dim3(512), 0, stream,
                     aB, pB, d1, d2, pos, pmin);
  hipLaunchKernelGGL(fin_k, dim3(1), dim3(1024), 0, stream,
                     pos, pmin, (float*)d_out);
}